// Round 4
// baseline (95.225 us; speedup 1.0000x reference)
//
#include <hip/hip_runtime.h>
#include <stdint.h>

#define D_DIM 128
#define NROW 8192          // 2B
#define L2EPS 1e-12f
// MFMA output = sim * 10/ln2 (exp2 arg): data pre-scaled by sqrt((10/ln2)/16),
// MX scales A=2^4 (131), B=2^0 (127).
#define SCALE_PRE 0.9495707f
#define LN2 0.6931471805599453f
#define NPART 50           // row slots 0..16, col slots 17..48, diag col 49

typedef __attribute__((ext_vector_type(4))) int   i32x4;
typedef __attribute__((ext_vector_type(8))) int   i32x8;
typedef __attribute__((ext_vector_type(4))) float f32x4;

#define AS1 __attribute__((address_space(1)))
#define AS3 __attribute__((address_space(3)))

static __device__ inline void gload_lds16(const void* g, void* l) {
    __builtin_amdgcn_global_load_lds((const AS1 uint32_t*)g, (AS3 uint32_t*)l, 16, 0, 0);
}

static __device__ inline i32x8 cat8(i32x4 lo, i32x4 hi) {
    i32x8 r;
    r[0] = lo[0]; r[1] = lo[1]; r[2] = lo[2]; r[3] = lo[3];
    r[4] = hi[0]; r[5] = hi[1]; r[6] = hi[2]; r[7] = hi[3];
    return r;
}

// Native 2^x: our arguments are |x| <= ~15, far from denormal/overflow edges.
static __device__ __forceinline__ float fexp2(float x) {
#if __has_builtin(__builtin_amdgcn_exp2f)
    return __builtin_amdgcn_exp2f(x);
#else
    float r;
    asm("v_exp_f32 %0, %1" : "=v"(r) : "v"(x));
    return r;
#endif
}

// Sum over the 16-lane DPP row on the VALU pipe. Result valid in lane 15.
static __device__ __forceinline__ float dpp_row_sum16(float v) {
    union { float f; int i; } u, s;
    u.f = v;
    s.i = __builtin_amdgcn_update_dpp(0, u.i, 0x118, 0xF, 0xF, true); u.f += s.f; // row_shr:8
    s.i = __builtin_amdgcn_update_dpp(0, u.i, 0x114, 0xF, 0xF, true); u.f += s.f; // row_shr:4
    s.i = __builtin_amdgcn_update_dpp(0, u.i, 0x112, 0xF, 0xF, true); u.f += s.f; // row_shr:2
    s.i = __builtin_amdgcn_update_dpp(0, u.i, 0x111, 0xF, 0xF, true); u.f += s.f; // row_shr:1
    return u.f;
}

// K1: L2-normalize rows of [x_i; x_j]; emit ONE fp8 e4m3 array (unchanged).
__global__ __launch_bounds__(256) void k_normalize(
        const float* __restrict__ xi, const float* __restrict__ xj,
        uint8_t* __restrict__ z8, float* __restrict__ pos_acc,
        float* __restrict__ logsum, unsigned* __restrict__ done_ct) {
    const int wave = threadIdx.x >> 6;
    const int lane = threadIdx.x & 63;
    const int row = blockIdx.x * 4 + wave;
    const float* src = (row < 4096) ? (xi + (size_t)row * D_DIM)
                                    : (xj + (size_t)(row - 4096) * D_DIM);
    float2 v = *(const float2*)(src + lane * 2);
    float ss = v.x * v.x + v.y * v.y;
#pragma unroll
    for (int m = 32; m >= 1; m >>= 1) ss += __shfl_xor(ss, m, 64);
    const float scale = SCALE_PRE / fmaxf(sqrtf(ss), L2EPS);
    const int pk = __builtin_amdgcn_cvt_pk_fp8_f32(v.x * scale, v.y * scale, 0, false);
    *(ushort*)(z8 + (size_t)row * D_DIM + lane * 2) = (ushort)pk;

    if (blockIdx.x == 0 && threadIdx.x == 0) {
        pos_acc[0] = 0.0f; logsum[0] = 0.0f; done_ct[0] = 0u;
    }
}

// K2 (paired-circulant, BIG-TILE): 256 heavy blocks + 64 diag blocks.
//  heavy bid<256: mb=bid>>4 (0..15), rb4=bid&15. A = 512 rows (bands
//   4rb4..4rb4+3), one band per wave, register-resident (8 frags/lane).
//   B = 5 bands base..base+4 (base=4rb4+2mb+1) in LDS (80 KB, XOR swizzle).
//   Wave w: j<8 -> B local w (distance 2mb+1), j>=8 -> local w+1 (2mb+2).
//   Coverage identical to the 128-tile scheme: distances 1..31 once (full
//   credit), distance 32 at mb=15 j>=8 double-enumerated -> e*=0.5, sub-tile
//   diagonal = positives. Col credits are single-writer PER WAVE (band local
//   k's dist-(2mb+1) credit comes only from A-band k) -> no cross-wave
//   reduction, no epilogue barriers in the heavy path.
//  diag bid>=256: rb=bid-256, 128x128 strictly-upper tile (verbatim R0 path),
//   dispatched last so the light blocks fill the tail.
// Traffic: 256x144KB + 64x32KB = 38 MB z8 reads (vs 50 MB at 128-tiles).
__global__ __launch_bounds__(256, 2) void k_gemm(
        const uint8_t* __restrict__ z8, float* __restrict__ part,
        float* __restrict__ pos_acc) {
    __shared__ __align__(16) uint8_t lds[81920];   // 5 bands x 128 rows x 128 B

    const int t = threadIdx.x;
    const int wave = t >> 6, lane = t & 63;
    const int quad = lane >> 4, lc = lane & 15;
    const int bid = blockIdx.x;

    if (bid < 256) {
        // ---------------- heavy path ----------------
        const int mb = bid >> 4;            // 0..15
        const int rb4 = bid & 15;           // 0..15
        const int base = 4 * rb4 + 2 * mb + 1;   // global band of local 0 (mod 64)

        // Stage B: 5 bands -> lds[band][row][unit], unit u holds global
        // 16B-unit u^(row&7). 5120 slots, 20 per thread.
#pragma unroll
        for (int q = 0; q < 20; q++) {
            const int s = q * 256 + t;
            const int bl = s >> 10;                  // local band 0..4
            const int r = (s >> 3) & 127;            // row in band
            const int g = (s & 7) ^ (r & 7);         // global unit
            const int gb = (base + bl) & 63;
            gload_lds16(z8 + (size_t)gb * 128 * D_DIM + (size_t)r * D_DIM + g * 16,
                        &lds[s * 16]);
        }

        // A frags: wave w owns band 4rb4+w; lane holds 32 B of row
        // (arow0 + i*16 + lc), bytes [quad*32,+32), i=0..7.
        const int arow0 = (4 * rb4 + wave) * 128;
        i32x8 afr[8];
        {
            const uint8_t* pa = z8 + (size_t)(arow0 + lc) * D_DIM + quad * 32;
#pragma unroll
            for (int i = 0; i < 8; i++) {
                i32x4 lo = *(const i32x4*)(pa + (size_t)i * 16 * D_DIM);
                i32x4 hi = *(const i32x4*)(pa + (size_t)i * 16 * D_DIM + 16);
                afr[i] = cat8(lo, hi);
            }
        }

        asm volatile("s_waitcnt vmcnt(0)" ::: "memory");
        __syncthreads();   // B resident; rest of heavy path is barrier-free

        float rs[8][4];
#pragma unroll
        for (int i = 0; i < 8; i++)
#pragma unroll
            for (int r = 0; r < 4; r++) rs[i][r] = 0.f;
        float cs[16];
#pragma unroll
        for (int j = 0; j < 16; j++) cs[j] = 0.f;
        float posp = 0.f;

        // B frag for (wave, j): local band w+(j>>3), row (j&7)*16+lc,
        // units (quad*2, quad*2+1) ^ (lc&7)  [row&7 == lc&7].
#define HB_FRAG(j)                                                            \
        i32x4 blo, bhi; {                                                     \
            const int rowb = (wave + ((j) >> 3)) * 16384 +                    \
                             (((j) & 7) * 16 + lc) * 128;                     \
            blo = *(const i32x4*)&lds[rowb + (((quad * 2)     ^ (lc & 7)) * 16)]; \
            bhi = *(const i32x4*)&lds[rowb + (((quad * 2 + 1) ^ (lc & 7)) * 16)]; \
        }                                                                     \
        const i32x8 bfr = cat8(blo, bhi);                                     \
        f32x4 acc[8];                                                         \
        {                                                                     \
            const f32x4 z4 = {0.f, 0.f, 0.f, 0.f};                            \
            _Pragma("unroll")                                                 \
            for (int i = 0; i < 8; i++)                                       \
                acc[i] = __builtin_amdgcn_mfma_scale_f32_16x16x128_f8f6f4(    \
                             afr[i], bfr, z4, 0, 0, 0, 131, 0, 127);          \
        }

#pragma unroll
        for (int j = 0; j < 8; j++) {        // distance 2mb+1: full credit
            HB_FRAG(j)
#pragma unroll
            for (int i = 0; i < 8; i++)
#pragma unroll
                for (int r = 0; r < 4; r++) {
                    const float e = fexp2(acc[i][r]);
                    rs[i][r] += e;
                    cs[j] += e;
                }
        }
        if (mb < 15) {                        // distance 2mb+2: full credit
#pragma unroll
            for (int j = 8; j < 16; j++) {
                HB_FRAG(j)
#pragma unroll
                for (int i = 0; i < 8; i++)
#pragma unroll
                    for (int r = 0; r < 4; r++) {
                        const float e = fexp2(acc[i][r]);
                        rs[i][r] += e;
                        cs[j] += e;
                    }
            }
        } else {                              // distance 32: halve; diag = positives
#pragma unroll
            for (int j = 8; j < 16; j++) {
                HB_FRAG(j)
#pragma unroll
                for (int i = 0; i < 8; i++)
#pragma unroll
                    for (int r = 0; r < 4; r++) {
                        const float s = acc[i][r];
                        const float e = 0.5f * fexp2(s);
                        if (((j & 7) == i) && (lc == quad * 4 + r)) posp += s;
                        rs[i][r] += e;
                        cs[j] += e;
                    }
            }
        }
#undef HB_FRAG

        // Row credits -> slot mb (single-writer, no barrier).
#pragma unroll
        for (int i = 0; i < 8; i++)
#pragma unroll
            for (int r = 0; r < 4; r++) {
                const float v = dpp_row_sum16(rs[i][r]);
                if (lc == 15)
                    part[(size_t)mb * NROW + arow0 + i * 16 + quad * 4 + r] = v;
            }

        // Col credits: quad-reduce within the wave; single-writer per
        // (slot, band) -> direct store, no cross-wave reduction.
#pragma unroll
        for (int j = 0; j < 16; j++) {
            cs[j] += __shfl_xor(cs[j], 16, 64);
            cs[j] += __shfl_xor(cs[j], 32, 64);
        }
        if (quad == 0) {
#pragma unroll
            for (int j = 0; j < 16; j++) {
                const int gb = (base + wave + (j >> 3)) & 63;
                const int slot = 17 + 2 * mb + (j >> 3);
                part[(size_t)slot * NROW + gb * 128 + (j & 7) * 16 + lc] = cs[j];
            }
        }

        if (mb == 15) {
#pragma unroll
            for (int mm = 32; mm >= 1; mm >>= 1) posp += __shfl_xor(posp, mm, 64);
            if (lane == 0) atomicAdd(pos_acc, posp);
        }
        return;
    }

    // ---------------- diag path (verbatim 128x128 strictly-upper) ----------------
    const int rb = bid - 256;
    const int rowbase = rb * 128;

    {
        const uint8_t* zb1 = z8 + (size_t)rb * 128 * D_DIM;
#pragma unroll
        for (int q = 0; q < 4; q++) {
            const int s = q * 256 + t;
            const int r = s >> 3;
            const int g = (s & 7) ^ (r & 7);
            gload_lds16(zb1 + (size_t)r * D_DIM + g * 16, &lds[s * 16]);
        }
    }

    i32x8 afr[2];
    {
        const uint8_t* pa = z8 + (size_t)(rowbase + wave * 32 + lc) * D_DIM + quad * 32;
#pragma unroll
        for (int i = 0; i < 2; i++) {
            i32x4 lo = *(const i32x4*)(pa + i * 16 * D_DIM);
            i32x4 hi = *(const i32x4*)(pa + i * 16 * D_DIM + 16);
            afr[i] = cat8(lo, hi);
        }
    }

    asm volatile("s_waitcnt vmcnt(0)" ::: "memory");
    __syncthreads();

    float rs[2][4] = {{0.f,0.f,0.f,0.f},{0.f,0.f,0.f,0.f}};
    float cs[16];
#pragma unroll
    for (int j = 0; j < 16; j++) cs[j] = 0.f;
    const int rl0 = wave * 32 + quad * 4;

#pragma unroll
    for (int j = 0; j < 8; j++) {
        i32x4 blo, bhi; {
            const int rowb = (j * 16 + lc) * D_DIM;
            blo = *(const i32x4*)&lds[rowb + (((quad * 2)     ^ (lc & 7)) * 16)];
            bhi = *(const i32x4*)&lds[rowb + (((quad * 2 + 1) ^ (lc & 7)) * 16)];
        }
        const i32x8 bfr = cat8(blo, bhi);
        const f32x4 z4 = {0.f, 0.f, 0.f, 0.f};
        f32x4 a0 = __builtin_amdgcn_mfma_scale_f32_16x16x128_f8f6f4(
                       afr[0], bfr, z4, 0, 0, 0, 131, 0, 127);
        f32x4 a1 = __builtin_amdgcn_mfma_scale_f32_16x16x128_f8f6f4(
                       afr[1], bfr, z4, 0, 0, 0, 131, 0, 127);
        const int cl = j * 16 + lc;
#pragma unroll
        for (int i = 0; i < 2; i++)
#pragma unroll
            for (int r = 0; r < 4; r++) {
                const float s = (i ? a1 : a0)[r];
                const float e = (cl > rl0 + i * 16 + r) ? fexp2(s) : 0.f;
                rs[i][r] += e;
                cs[j] += e;
            }
    }

#pragma unroll
    for (int i = 0; i < 2; i++)
#pragma unroll
        for (int r = 0; r < 4; r++) {
            const float v = dpp_row_sum16(rs[i][r]);
            if (lc == 15)
                part[(size_t)16 * NROW + rowbase + rl0 + i * 16 + r] = v;
        }

#pragma unroll
    for (int j = 0; j < 16; j++) {
        cs[j] += __shfl_xor(cs[j], 16, 64);
        cs[j] += __shfl_xor(cs[j], 32, 64);
    }
    __syncthreads();                    // all B reads done; reuse LDS
    float* colred = (float*)lds;        // [4][256]
    if (quad == 0) {
#pragma unroll
        for (int j = 0; j < 16; j++)
            colred[wave * 256 + j * 16 + lc] = cs[j];
    }
    __syncthreads();
    if (t < 128) {
        const float v = colred[t] + colred[256 + t] + colred[512 + t] + colred[768 + t];
        part[(size_t)49 * NROW + rb * 128 + t] = v;
    }
}

// K3 (fused logsum + combine): unchanged.
__global__ __launch_bounds__(256) void k_logsum(
        const float* __restrict__ part, float* __restrict__ pos_acc,
        float* __restrict__ logsum, unsigned* __restrict__ done_ct,
        float* __restrict__ out) {
    const int row = blockIdx.x * 256 + threadIdx.x;
    float d = 0.f;
#pragma unroll
    for (int p = 0; p < NPART; p++) d += part[(size_t)p * NROW + row];
    float v = __logf(d);
#pragma unroll
    for (int m = 32; m >= 1; m >>= 1) v += __shfl_xor(v, m, 64);
    if ((threadIdx.x & 63) == 0) atomicAdd(logsum, v);
    __threadfence();
    __syncthreads();
    if (threadIdx.x == 0) {
        const unsigned prev = atomicAdd(done_ct, 1u);
        if (prev == gridDim.x - 1) {
            __threadfence();
            const float ls = atomicAdd(logsum, 0.0f);
            const float pp = atomicAdd(pos_acc, 0.0f);
            out[0] = (ls - pp * LN2) / (float)NROW;
        }
    }
}

extern "C" void kernel_launch(void* const* d_in, const int* in_sizes, int n_in,
                              void* d_out, int out_size, void* d_ws, size_t ws_size,
                              hipStream_t stream) {
    const float* xi = (const float*)d_in[0];
    const float* xj = (const float*)d_in[1];
    uint8_t* z8 = (uint8_t*)d_ws;                                // 1 MB fp8
    float* part = (float*)(z8 + (size_t)NROW * D_DIM);           // 50 x 8192 f32
    float* pos_acc = part + (size_t)NPART * NROW;
    float* logsum = pos_acc + 1;
    unsigned* done_ct = (unsigned*)(logsum + 1);
    float* out = (float*)d_out;

    hipLaunchKernelGGL(k_normalize, dim3(NROW / 4), dim3(256), 0, stream,
                       xi, xj, z8, pos_acc, logsum, done_ct);
    hipLaunchKernelGGL(k_gemm, dim3(256 + 64), dim3(256), 0, stream,
                       z8, part, pos_acc);
    hipLaunchKernelGGL(k_logsum, dim3(NROW / 256), dim3(256), 0, stream,
                       part, pos_acc, logsum, done_ct, out);
}

// Round 5
// 78.142 us; speedup vs baseline: 1.2186x; 1.2186x over previous
//
#include <hip/hip_runtime.h>
#include <stdint.h>

#define D_DIM 128
#define NROW 8192          // 2B
#define L2EPS 1e-12f
// MFMA output = sim * 10/ln2 (exp2 arg): data pre-scaled by sqrt((10/ln2)/16),
// MX scales A=2^4 (131), B=2^0 (127).
#define SCALE_PRE 0.9495707f
#define LN2 0.6931471805599453f

typedef __attribute__((ext_vector_type(4))) int   i32x4;
typedef __attribute__((ext_vector_type(8))) int   i32x8;
typedef __attribute__((ext_vector_type(4))) float f32x4;

#define AS1 __attribute__((address_space(1)))
#define AS3 __attribute__((address_space(3)))

static __device__ inline void gload_lds16(const void* g, void* l) {
    __builtin_amdgcn_global_load_lds((const AS1 uint32_t*)g, (AS3 uint32_t*)l, 16, 0, 0);
}

static __device__ inline i32x8 cat8(i32x4 lo, i32x4 hi) {
    i32x8 r;
    r[0] = lo[0]; r[1] = lo[1]; r[2] = lo[2]; r[3] = lo[3];
    r[4] = hi[0]; r[5] = hi[1]; r[6] = hi[2]; r[7] = hi[3];
    return r;
}

// Native 2^x: our arguments are |x| <= ~15 (sim*10/ln2), far from the
// denormal/overflow edges the OCML exp2f wrapper guards -> raw v_exp_f32.
static __device__ __forceinline__ float fexp2(float x) {
#if __has_builtin(__builtin_amdgcn_exp2f)
    return __builtin_amdgcn_exp2f(x);
#else
    float r;
    asm("v_exp_f32 %0, %1" : "=v"(r) : "v"(x));
    return r;
#endif
}

// Sum over the 16-lane DPP row on the VALU pipe (no ds_bpermute / LDS pipe).
// Result valid in lane 15 of each 16-lane row.
static __device__ __forceinline__ float dpp_row_sum16(float v) {
    union { float f; int i; } u, s;
    u.f = v;
    s.i = __builtin_amdgcn_update_dpp(0, u.i, 0x118, 0xF, 0xF, true); u.f += s.f; // row_shr:8
    s.i = __builtin_amdgcn_update_dpp(0, u.i, 0x114, 0xF, 0xF, true); u.f += s.f; // row_shr:4
    s.i = __builtin_amdgcn_update_dpp(0, u.i, 0x112, 0xF, 0xF, true); u.f += s.f; // row_shr:2
    s.i = __builtin_amdgcn_update_dpp(0, u.i, 0x111, 0xF, 0xF, true); u.f += s.f; // row_shr:1
    return u.f;
}

// K1: L2-normalize rows of [x_i; x_j]; emit ONE fp8 e4m3 array
// z8 = fp8(z * SCALE_PRE). Also zeroes the row/col credit accumulators
// (k_gemm atomically accumulates into them; workspace is re-poisoned
// between iterations) -- stream-ordered before k_gemm.
__global__ __launch_bounds__(256) void k_normalize(
        const float* __restrict__ xi, const float* __restrict__ xj,
        uint8_t* __restrict__ z8, float* __restrict__ rowacc,
        float* __restrict__ colacc, float* __restrict__ pos_acc,
        float* __restrict__ logsum, unsigned* __restrict__ done_ct) {
    const int wave = threadIdx.x >> 6;
    const int lane = threadIdx.x & 63;
    const int row = blockIdx.x * 4 + wave;
    const float* src = (row < 4096) ? (xi + (size_t)row * D_DIM)
                                    : (xj + (size_t)(row - 4096) * D_DIM);
    float2 v = *(const float2*)(src + lane * 2);
    float ss = v.x * v.x + v.y * v.y;
#pragma unroll
    for (int m = 32; m >= 1; m >>= 1) ss += __shfl_xor(ss, m, 64);
    const float scale = SCALE_PRE / fmaxf(sqrtf(ss), L2EPS);
    const int pk = __builtin_amdgcn_cvt_pk_fp8_f32(v.x * scale, v.y * scale, 0, false);
    *(ushort*)(z8 + (size_t)row * D_DIM + lane * 2) = (ushort)pk;

    // Zero accumulators: blocks 0..31 -> rowacc, 32..63 -> colacc.
    if (blockIdx.x < 32)
        rowacc[blockIdx.x * 256 + threadIdx.x] = 0.0f;
    else if (blockIdx.x < 64)
        colacc[(blockIdx.x - 32) * 256 + threadIdx.x] = 0.0f;

    if (blockIdx.x == 0 && threadIdx.x == 0) {
        pos_acc[0] = 0.0f; logsum[0] = 0.0f; done_ct[0] = 0u;
    }
}

// K2 (paired-circulant symmetric, R0 structure): block (mb=bid>>6 in 0..16,
// rb=bid&63).
//  mb<16 : rows band rb x col bands c1=(rb+2mb+1)%64, c2=(rb+2mb+2)%64
//          (128x256 tile). Distances 1..31 covered once (full credit);
//          mb==15's second half = distance 32, double-enumerated -> e*=0.5,
//          sub-tile diagonal = positive pairs (both directions accumulated).
//  mb==16: diagonal tile rb x rb, strictly-upper (c>r) only.
// Credits go STRAIGHT to rowacc/colacc via atomicAdd (f32, device-scope;
// <=33 adds per address, ~288/block) -- this deletes the old 50-slot part
// array, the colred LDS round-trip, and BOTH epilogue barriers. B bands
// LDS-resident (XOR swizzle) after ONE barrier (the only one).
// MFMA: mfma_scale_f32_16x16x128_f8f6f4, scale_a=131 (x16), scale_b=127 (x1).
__global__ __launch_bounds__(256) void k_gemm(
        const uint8_t* __restrict__ z8, float* __restrict__ rowacc,
        float* __restrict__ colacc, float* __restrict__ pos_acc) {
    __shared__ __align__(16) uint8_t lds[32768];   // 256 B-rows x 128 B fp8

    const int t = threadIdx.x;
    const int wave = t >> 6, lane = t & 63;
    const int quad = lane >> 4, lc = lane & 15;

    const int mb = blockIdx.x >> 6;     // 0..16
    const int rb = blockIdx.x & 63;
    const int rowbase = rb * 128;
    const bool diag = (mb == 16);
    const int c1 = diag ? rb : (rb + 2 * mb + 1) & 63;
    const int c2 = (rb + 2 * mb + 2) & 63;          // unused when diag

    // Stage B: band c1 -> lds rows 0..127, band c2 -> rows 128..255.
    // Slot s: row r=s>>3, slot-unit u holds global 16B-unit u^(r&7).
    {
        const uint8_t* zb1 = z8 + (size_t)c1 * 128 * D_DIM;
#pragma unroll
        for (int q = 0; q < 4; q++) {
            const int s = q * 256 + t;
            const int r = s >> 3;
            const int g = (s & 7) ^ (r & 7);
            gload_lds16(zb1 + (size_t)r * D_DIM + g * 16, &lds[s * 16]);
        }
        if (!diag) {
            const uint8_t* zb2 = z8 + (size_t)c2 * 128 * D_DIM;
#pragma unroll
            for (int q = 0; q < 4; q++) {
                const int s = q * 256 + t;
                const int r = s >> 3;
                const int g = (s & 7) ^ (r & 7);
                gload_lds16(zb2 + (size_t)r * D_DIM + g * 16, &lds[16384 + s * 16]);
            }
        }
    }

    // A fragments: 32 B of row (rowbase + wave*32 + i*16 + lc), bytes [quad*32,+32).
    i32x8 afr[2];
    {
        const uint8_t* pa = z8 + (size_t)(rowbase + wave * 32 + lc) * D_DIM + quad * 32;
#pragma unroll
        for (int i = 0; i < 2; i++) {
            i32x4 lo = *(const i32x4*)(pa + i * 16 * D_DIM);
            i32x4 hi = *(const i32x4*)(pa + i * 16 * D_DIM + 16);
            afr[i] = cat8(lo, hi);
        }
    }

    asm volatile("s_waitcnt vmcnt(0)" ::: "memory");
    __syncthreads();   // B resident; everything below is barrier-free

    float rs[2][4] = {{0.f,0.f,0.f,0.f},{0.f,0.f,0.f,0.f}};
    float cs[16];
#pragma unroll
    for (int j = 0; j < 16; j++) cs[j] = 0.f;
    float posp = 0.f;
    const int rl0 = wave * 32 + quad * 4;   // local row = rl0 + i*16 + r

    // B-row jr = j*16+lc; jr&7 == lc&7, so read slot-units (quad*2..+1)^(lc&7).
#define MFMA_J(j, A0, A1)                                                     \
    i32x4 blo, bhi; {                                                         \
        const int rowb = ((j) * 16 + lc) * D_DIM;                             \
        blo = *(const i32x4*)&lds[rowb + (((quad * 2)     ^ (lc & 7)) * 16)]; \
        bhi = *(const i32x4*)&lds[rowb + (((quad * 2 + 1) ^ (lc & 7)) * 16)]; \
    }                                                                         \
    const i32x8 bfr = cat8(blo, bhi);                                         \
    f32x4 z4 = {0.f, 0.f, 0.f, 0.f};                                          \
    f32x4 A0 = __builtin_amdgcn_mfma_scale_f32_16x16x128_f8f6f4(              \
                   afr[0], bfr, z4, 0, 0, 0, 131, 0, 127);                    \
    f32x4 A1 = __builtin_amdgcn_mfma_scale_f32_16x16x128_f8f6f4(              \
                   afr[1], bfr, z4, 0, 0, 0, 131, 0, 127);

    if (!diag) {
#pragma unroll
        for (int j = 0; j < 8; j++) {        // band c1: always full credit
            MFMA_J(j, a0, a1)
#pragma unroll
            for (int r = 0; r < 4; r++) {
                const float e0 = fexp2(a0[r]);
                const float e1 = fexp2(a1[r]);
                rs[0][r] += e0;
                rs[1][r] += e1;
                cs[j] += e0 + e1;
            }
        }
        if (mb < 15) {                        // band c2: full credit
#pragma unroll
            for (int j = 8; j < 16; j++) {
                MFMA_J(j, a0, a1)
#pragma unroll
                for (int r = 0; r < 4; r++) {
                    const float e0 = fexp2(a0[r]);
                    const float e1 = fexp2(a1[r]);
                    rs[0][r] += e0;
                    rs[1][r] += e1;
                    cs[j] += e0 + e1;
                }
            }
        } else {                              // distance-32: halve; diag = positives
#pragma unroll
            for (int j = 8; j < 16; j++) {
                MFMA_J(j, a0, a1)
                const int clb = (j - 8) * 16 + lc;   // band-local col
#pragma unroll
                for (int i = 0; i < 2; i++)
#pragma unroll
                    for (int r = 0; r < 4; r++) {
                        const float s = (i ? a1 : a0)[r];
                        const float e = 0.5f * fexp2(s);
                        if (clb == rl0 + i * 16 + r) posp += s;
                        rs[i][r] += e;
                        cs[j] += e;
                    }
            }
        }
    } else {                                  // diagonal tile: strictly upper
#pragma unroll
        for (int j = 0; j < 8; j++) {
            MFMA_J(j, a0, a1)
            const int cl = j * 16 + lc;
#pragma unroll
            for (int i = 0; i < 2; i++)
#pragma unroll
                for (int r = 0; r < 4; r++) {
                    const float s = (i ? a1 : a0)[r];
                    const float e = (cl > rl0 + i * 16 + r) ? fexp2(s) : 0.f;
                    rs[i][r] += e;
                    cs[j] += e;
                }
        }
    }
#undef MFMA_J

    // Row credits: DPP row-sum over the 16 col-lanes (VALU pipe; result
    // lands in lane 15), then one atomicAdd per output row.
#pragma unroll
    for (int i = 0; i < 2; i++)
#pragma unroll
        for (int r = 0; r < 4; r++) {
            const float v = dpp_row_sum16(rs[i][r]);
            if (lc == 15)
                atomicAdd(&rowacc[rowbase + rl0 + i * 16 + r], v);
        }

    // Col credits: quad-reduce within the wave (2 shfl), then quad 0 lanes
    // atomicAdd straight to the global column -- no LDS, no barriers.
#pragma unroll
    for (int j = 0; j < 16; j++) {
        cs[j] += __shfl_xor(cs[j], 16, 64);
        cs[j] += __shfl_xor(cs[j], 32, 64);
    }
    if (quad == 0) {
#pragma unroll
        for (int j = 0; j < 16; j++) {
            if (diag && j >= 8) break;       // diag tile only has 8 j's
            const int band = (j < 8) ? c1 : c2;
            atomicAdd(&colacc[band * 128 + (j & 7) * 16 + lc], cs[j]);
        }
    }

    if (mb == 15) {
#pragma unroll
        for (int mm = 32; mm >= 1; mm >>= 1) posp += __shfl_xor(posp, mm, 64);
        if (lane == 0) atomicAdd(pos_acc, posp);
    }
}

// K3 (fused logsum + combine): 32 blocks, one row per thread; last block
// (atomic counter) writes the final loss. Denominator = rowacc + colacc
// (2 loads/row instead of the old 50 part-slots). pos_acc holds scaled sim
// over both appearances of each positive pair -> factor ln2.
__global__ __launch_bounds__(256) void k_logsum(
        const float* __restrict__ rowacc, const float* __restrict__ colacc,
        float* __restrict__ pos_acc, float* __restrict__ logsum,
        unsigned* __restrict__ done_ct, float* __restrict__ out) {
    const int row = blockIdx.x * 256 + threadIdx.x;
    const float d = rowacc[row] + colacc[row];
    float v = __logf(d);
#pragma unroll
    for (int m = 32; m >= 1; m >>= 1) v += __shfl_xor(v, m, 64);
    if ((threadIdx.x & 63) == 0) atomicAdd(logsum, v);
    __threadfence();
    __syncthreads();
    if (threadIdx.x == 0) {
        const unsigned prev = atomicAdd(done_ct, 1u);
        if (prev == gridDim.x - 1) {          // last block: all adds visible
            __threadfence();
            const float ls = atomicAdd(logsum, 0.0f);
            const float pp = atomicAdd(pos_acc, 0.0f);
            out[0] = (ls - pp * LN2) / (float)NROW;
        }
    }
}

extern "C" void kernel_launch(void* const* d_in, const int* in_sizes, int n_in,
                              void* d_out, int out_size, void* d_ws, size_t ws_size,
                              hipStream_t stream) {
    const float* xi = (const float*)d_in[0];
    const float* xj = (const float*)d_in[1];
    uint8_t* z8 = (uint8_t*)d_ws;                                // 1 MB fp8
    float* rowacc = (float*)(z8 + (size_t)NROW * D_DIM);         // 8192 f32
    float* colacc = rowacc + NROW;                               // 8192 f32
    float* pos_acc = colacc + NROW;
    float* logsum = pos_acc + 1;
    unsigned* done_ct = (unsigned*)(logsum + 1);
    float* out = (float*)d_out;

    hipLaunchKernelGGL(k_normalize, dim3(NROW / 4), dim3(256), 0, stream,
                       xi, xj, z8, rowacc, colacc, pos_acc, logsum, done_ct);
    hipLaunchKernelGGL(k_gemm, dim3(17 * 64), dim3(256), 0, stream,
                       z8, rowacc, colacc, pos_acc);
    hipLaunchKernelGGL(k_logsum, dim3(NROW / 256), dim3(256), 0, stream,
                       rowacc, colacc, pos_acc, logsum, done_ct, out);
}

// Round 6
// 76.876 us; speedup vs baseline: 1.2387x; 1.0165x over previous
//
#include <hip/hip_runtime.h>
#include <stdint.h>

#define D_DIM 128
#define NROW 8192          // 2B
#define L2EPS 1e-12f
// MFMA output = sim * 10/ln2 (exp2 arg): data pre-scaled by sqrt((10/ln2)/16),
// MX scales A=2^4 (131), B=2^0 (127).
#define SCALE_PRE 0.9495707f
#define LN2 0.6931471805599453f

typedef __attribute__((ext_vector_type(4))) int   i32x4;
typedef __attribute__((ext_vector_type(8))) int   i32x8;
typedef __attribute__((ext_vector_type(4))) float f32x4;

#define AS1 __attribute__((address_space(1)))
#define AS3 __attribute__((address_space(3)))

static __device__ inline void gload_lds16(const void* g, void* l) {
    __builtin_amdgcn_global_load_lds((const AS1 uint32_t*)g, (AS3 uint32_t*)l, 16, 0, 0);
}

static __device__ inline i32x8 cat8(i32x4 lo, i32x4 hi) {
    i32x8 r;
    r[0] = lo[0]; r[1] = lo[1]; r[2] = lo[2]; r[3] = lo[3];
    r[4] = hi[0]; r[5] = hi[1]; r[6] = hi[2]; r[7] = hi[3];
    return r;
}

// Native 2^x: arguments are |x| <= ~15, far from denormal/overflow edges.
static __device__ __forceinline__ float fexp2(float x) {
#if __has_builtin(__builtin_amdgcn_exp2f)
    return __builtin_amdgcn_exp2f(x);
#else
    float r;
    asm("v_exp_f32 %0, %1" : "=v"(r) : "v"(x));
    return r;
#endif
}

// Sum over the 16-lane DPP row on the VALU pipe. Result valid in lane 15.
static __device__ __forceinline__ float dpp_row_sum16(float v) {
    union { float f; int i; } u, s;
    u.f = v;
    s.i = __builtin_amdgcn_update_dpp(0, u.i, 0x118, 0xF, 0xF, true); u.f += s.f; // row_shr:8
    s.i = __builtin_amdgcn_update_dpp(0, u.i, 0x114, 0xF, 0xF, true); u.f += s.f; // row_shr:4
    s.i = __builtin_amdgcn_update_dpp(0, u.i, 0x112, 0xF, 0xF, true); u.f += s.f; // row_shr:2
    s.i = __builtin_amdgcn_update_dpp(0, u.i, 0x111, 0xF, 0xF, true); u.f += s.f; // row_shr:1
    return u.f;
}

// K1: L2-normalize rows of [x_i; x_j]; emit ONE fp8 e4m3 array
// z8 = fp8(z * SCALE_PRE). Also zeroes the row/col credit accumulators.
__global__ __launch_bounds__(256) void k_normalize(
        const float* __restrict__ xi, const float* __restrict__ xj,
        uint8_t* __restrict__ z8, float* __restrict__ rowacc,
        float* __restrict__ colacc, float* __restrict__ pos_acc,
        float* __restrict__ logsum, unsigned* __restrict__ done_ct) {
    const int wave = threadIdx.x >> 6;
    const int lane = threadIdx.x & 63;
    const int row = blockIdx.x * 4 + wave;
    const float* src = (row < 4096) ? (xi + (size_t)row * D_DIM)
                                    : (xj + (size_t)(row - 4096) * D_DIM);
    float2 v = *(const float2*)(src + lane * 2);
    float ss = v.x * v.x + v.y * v.y;
#pragma unroll
    for (int m = 32; m >= 1; m >>= 1) ss += __shfl_xor(ss, m, 64);
    const float scale = SCALE_PRE / fmaxf(sqrtf(ss), L2EPS);
    const int pk = __builtin_amdgcn_cvt_pk_fp8_f32(v.x * scale, v.y * scale, 0, false);
    *(ushort*)(z8 + (size_t)row * D_DIM + lane * 2) = (ushort)pk;

    if (blockIdx.x < 32)
        rowacc[blockIdx.x * 256 + threadIdx.x] = 0.0f;
    else if (blockIdx.x < 64)
        colacc[(blockIdx.x - 32) * 256 + threadIdx.x] = 0.0f;

    if (blockIdx.x == 0 && threadIdx.x == 0) {
        pos_acc[0] = 0.0f; logsum[0] = 0.0f; done_ct[0] = 0u;
    }
}

// K2 (4-distance circulant, 512-thread blocks): heavy bid<512: mb=bid>>6
// (0..7), b=bid&63. A = 256 rows: bands {b, b+1}, waves 0-3 own band b
// (32 rows each), waves 4-7 own band b+1. B = bands b1=b+4mb+2, b2=b+4mb+4
// staged in LDS (32 KB, XOR swizzle). Realized distances per block:
// b->b1=4mb+2, b->b2=4mb+4, (b+1)->b1=4mb+1, (b+1)->b2=4mb+3 -- over
// mb=0..7, b=0..63 this tiles distances 1..32 exactly once. d=32 (mb=7,
// waves<4, j>=8) is double-enumerated over b -> e*=0.5 + positives.
// Same per-wave inner loop as before; HALF the blocks => half the B-panel
// staging traffic (16.4 MB vs 33 MB). Split-wait staging: b1 -> A -> b2,
// vmcnt(2)+barrier lets j<8 compute while b2 streams in.
// diag bid>=512: rb=bid-512, 128x128 strictly-upper, 8 waves x 16 rows.
// Credits -> rowacc/colacc via atomicAdd (R5 scheme, no epilogue barriers).
__global__ __launch_bounds__(512) void k_gemm(
        const uint8_t* __restrict__ z8, float* __restrict__ rowacc,
        float* __restrict__ colacc, float* __restrict__ pos_acc) {
    __shared__ __align__(16) uint8_t lds[32768];   // 256 B-rows x 128 B fp8

    const int t = threadIdx.x;
    const int wave = t >> 6, lane = t & 63;
    const int quad = lane >> 4, lc = lane & 15;
    const int bid = blockIdx.x;

    const f32x4 z4 = {0.f, 0.f, 0.f, 0.f};

    if (bid < 512) {
        // ---------------- heavy path ----------------
        const int mb = bid >> 6;                 // 0..7
        const int b  = bid & 63;
        const int b1 = (b + 4 * mb + 2) & 63;
        const int b2 = (b + 4 * mb + 4) & 63;

        // Stage band b1 -> lds rows 0..127 (slots 0..1023, 2/thread).
#pragma unroll
        for (int q = 0; q < 2; q++) {
            const int s = q * 512 + t;
            const int r = s >> 3;                // 0..127
            const int g = (s & 7) ^ (r & 7);
            gload_lds16(z8 + (size_t)b1 * 128 * D_DIM + (size_t)r * D_DIM + g * 16,
                        &lds[s * 16]);
        }
        asm volatile("" ::: "memory");           // pin: b1 stages before A loads

        // A frags: wave w owns band (w<4 ? b : b+1), rows (w&3)*32 .. +31.
        const int ab = (wave < 4) ? b : ((b + 1) & 63);
        const int arow0 = ab * 128 + (wave & 3) * 32;
        i32x8 afr[2];
        {
            const uint8_t* pa = z8 + (size_t)(arow0 + lc) * D_DIM + quad * 32;
#pragma unroll
            for (int i = 0; i < 2; i++) {
                i32x4 lo = *(const i32x4*)(pa + i * 16 * D_DIM);
                i32x4 hi = *(const i32x4*)(pa + i * 16 * D_DIM + 16);
                afr[i] = cat8(lo, hi);
            }
        }
        asm volatile("" ::: "memory");           // pin: A loads before b2 stages

        // Stage band b2 -> lds rows 128..255 (slots 1024..2047).
#pragma unroll
        for (int q = 2; q < 4; q++) {
            const int s = q * 512 + t;
            const int r = s >> 3;                // 128..255
            const int g = (s & 7) ^ (r & 7);
            gload_lds16(z8 + (size_t)b2 * 128 * D_DIM + (size_t)(r - 128) * D_DIM + g * 16,
                        &lds[s * 16]);
        }

        // Wait b1 + A (leave b2's 2 loads in flight), then barrier.
        asm volatile("s_waitcnt vmcnt(2)" ::: "memory");
        __syncthreads();

        f32x4 rs4[2] = {z4, z4};
        float cs[16];
#pragma unroll
        for (int j = 0; j < 16; j++) cs[j] = 0.f;
        float posp = 0.f;

        // B-row jr = j*16+lc; jr&7 == lc&7 -> slot-units (quad*2..+1)^(lc&7).
#define MFMA_J(j, A0, A1)                                                     \
    i32x4 blo, bhi; {                                                         \
        const int rowb = ((j) * 16 + lc) * D_DIM;                             \
        blo = *(const i32x4*)&lds[rowb + (((quad * 2)     ^ (lc & 7)) * 16)]; \
        bhi = *(const i32x4*)&lds[rowb + (((quad * 2 + 1) ^ (lc & 7)) * 16)]; \
    }                                                                         \
    const i32x8 bfr = cat8(blo, bhi);                                         \
    f32x4 A0 = __builtin_amdgcn_mfma_scale_f32_16x16x128_f8f6f4(              \
                   afr[0], bfr, z4, 0, 0, 0, 131, 0, 127);                    \
    f32x4 A1 = __builtin_amdgcn_mfma_scale_f32_16x16x128_f8f6f4(              \
                   afr[1], bfr, z4, 0, 0, 0, 131, 0, 127);

#define CREDIT_FULL(j, A0, A1)                                                \
    {                                                                         \
        f32x4 ev0, ev1;                                                       \
        ev0[0] = fexp2(A0[0]); ev0[1] = fexp2(A0[1]);                         \
        ev0[2] = fexp2(A0[2]); ev0[3] = fexp2(A0[3]);                         \
        ev1[0] = fexp2(A1[0]); ev1[1] = fexp2(A1[1]);                         \
        ev1[2] = fexp2(A1[2]); ev1[3] = fexp2(A1[3]);                         \
        rs4[0] += ev0;                                                        \
        rs4[1] += ev1;                                                        \
        cs[j] += ((ev0[0] + ev0[1]) + (ev0[2] + ev0[3]))                      \
               + ((ev1[0] + ev1[1]) + (ev1[2] + ev1[3]));                     \
    }

#pragma unroll
        for (int j = 0; j < 8; j++) {            // band b1: always full credit
            MFMA_J(j, a0, a1)
            CREDIT_FULL(j, a0, a1)
        }

        // Band b2 now resident.
        asm volatile("s_waitcnt vmcnt(0)" ::: "memory");
        __syncthreads();

        if (mb < 7) {                             // band b2: full credit
#pragma unroll
            for (int j = 8; j < 16; j++) {
                MFMA_J(j, a0, a1)
                CREDIT_FULL(j, a0, a1)
            }
        } else {
            // mb==7, j>=8: distance 32 for waves 0-3 (halve + positives);
            // distance 31 for waves 4-7 (full credit). Wave-uniform branch.
            if (wave < 4) {
#pragma unroll
                for (int j = 8; j < 16; j++) {
                    MFMA_J(j, a0, a1)
                    const int clb = (j - 8) * 16 + lc;   // band-local col
                    const int rl0 = wave * 32 + quad * 4;
#pragma unroll
                    for (int i = 0; i < 2; i++)
#pragma unroll
                        for (int r = 0; r < 4; r++) {
                            const float s = (i ? a1 : a0)[r];
                            const float e = 0.5f * fexp2(s);
                            if (clb == rl0 + i * 16 + r) posp += s;
                            rs4[i][r] += e;
                            cs[j] += e;
                        }
                }
            } else {
#pragma unroll
                for (int j = 8; j < 16; j++) {
                    MFMA_J(j, a0, a1)
                    CREDIT_FULL(j, a0, a1)
                }
            }
        }
#undef CREDIT_FULL
#undef MFMA_J

        // Row credits: DPP row-sum (lane 15 holds result) -> atomicAdd.
#pragma unroll
        for (int i = 0; i < 2; i++)
#pragma unroll
            for (int r = 0; r < 4; r++) {
                const float v = dpp_row_sum16(rs4[i][r]);
                if (lc == 15)
                    atomicAdd(&rowacc[arow0 + i * 16 + quad * 4 + r], v);
            }

        // Col credits: quad-reduce (2 shfl), quad 0 atomicAdds.
#pragma unroll
        for (int j = 0; j < 16; j++) {
            cs[j] += __shfl_xor(cs[j], 16, 64);
            cs[j] += __shfl_xor(cs[j], 32, 64);
        }
        if (quad == 0) {
#pragma unroll
            for (int j = 0; j < 16; j++) {
                const int band = (j < 8) ? b1 : b2;
                atomicAdd(&colacc[band * 128 + (j & 7) * 16 + lc], cs[j]);
            }
        }

        if (mb == 7 && wave < 4) {
#pragma unroll
            for (int mm = 32; mm >= 1; mm >>= 1) posp += __shfl_xor(posp, mm, 64);
            if (lane == 0) atomicAdd(pos_acc, posp);
        }
        return;
    }

    // ---------------- diag path: 128x128 strictly-upper, 8 waves x 16 rows --
    const int rb = bid - 512;
    {
        const uint8_t* zb = z8 + (size_t)rb * 128 * D_DIM;
#pragma unroll
        for (int q = 0; q < 2; q++) {
            const int s = q * 512 + t;           // 0..1023
            const int r = s >> 3;                // 0..127
            const int g = (s & 7) ^ (r & 7);
            gload_lds16(zb + (size_t)r * D_DIM + g * 16, &lds[s * 16]);
        }
    }

    i32x8 afr;
    {
        const uint8_t* pa = z8 + (size_t)(rb * 128 + wave * 16 + lc) * D_DIM + quad * 32;
        i32x4 lo = *(const i32x4*)pa;
        i32x4 hi = *(const i32x4*)(pa + 16);
        afr = cat8(lo, hi);
    }

    asm volatile("s_waitcnt vmcnt(0)" ::: "memory");
    __syncthreads();

    f32x4 rs4 = z4;
    float cs[8];
#pragma unroll
    for (int j = 0; j < 8; j++) cs[j] = 0.f;
    const int rl0 = wave * 16 + quad * 4;        // local row = rl0 + r

#pragma unroll
    for (int j = 0; j < 8; j++) {
        i32x4 blo, bhi; {
            const int rowb = (j * 16 + lc) * D_DIM;
            blo = *(const i32x4*)&lds[rowb + (((quad * 2)     ^ (lc & 7)) * 16)];
            bhi = *(const i32x4*)&lds[rowb + (((quad * 2 + 1) ^ (lc & 7)) * 16)];
        }
        const i32x8 bfr = cat8(blo, bhi);
        f32x4 a0 = __builtin_amdgcn_mfma_scale_f32_16x16x128_f8f6f4(
                       afr, bfr, z4, 0, 0, 0, 131, 0, 127);
        const int cl = j * 16 + lc;
#pragma unroll
        for (int r = 0; r < 4; r++) {
            const float e = (cl > rl0 + r) ? fexp2(a0[r]) : 0.f;
            rs4[r] += e;
            cs[j] += e;
        }
    }

#pragma unroll
    for (int r = 0; r < 4; r++) {
        const float v = dpp_row_sum16(rs4[r]);
        if (lc == 15)
            atomicAdd(&rowacc[rb * 128 + rl0 + r], v);
    }

#pragma unroll
    for (int j = 0; j < 8; j++) {
        cs[j] += __shfl_xor(cs[j], 16, 64);
        cs[j] += __shfl_xor(cs[j], 32, 64);
    }
    if (quad == 0) {
#pragma unroll
        for (int j = 0; j < 8; j++)
            atomicAdd(&colacc[rb * 128 + j * 16 + lc], cs[j]);
    }
}

// K3 (fused logsum + combine): 32 blocks, one row per thread; last block
// writes the final loss. Denominator = rowacc + colacc.
__global__ __launch_bounds__(256) void k_logsum(
        const float* __restrict__ rowacc, const float* __restrict__ colacc,
        float* __restrict__ pos_acc, float* __restrict__ logsum,
        unsigned* __restrict__ done_ct, float* __restrict__ out) {
    const int row = blockIdx.x * 256 + threadIdx.x;
    const float d = rowacc[row] + colacc[row];
    float v = __logf(d);
#pragma unroll
    for (int m = 32; m >= 1; m >>= 1) v += __shfl_xor(v, m, 64);
    if ((threadIdx.x & 63) == 0) atomicAdd(logsum, v);
    __threadfence();
    __syncthreads();
    if (threadIdx.x == 0) {
        const unsigned prev = atomicAdd(done_ct, 1u);
        if (prev == gridDim.x - 1) {
            __threadfence();
            const float ls = atomicAdd(logsum, 0.0f);
            const float pp = atomicAdd(pos_acc, 0.0f);
            out[0] = (ls - pp * LN2) / (float)NROW;
        }
    }
}

extern "C" void kernel_launch(void* const* d_in, const int* in_sizes, int n_in,
                              void* d_out, int out_size, void* d_ws, size_t ws_size,
                              hipStream_t stream) {
    const float* xi = (const float*)d_in[0];
    const float* xj = (const float*)d_in[1];
    uint8_t* z8 = (uint8_t*)d_ws;                                // 1 MB fp8
    float* rowacc = (float*)(z8 + (size_t)NROW * D_DIM);         // 8192 f32
    float* colacc = rowacc + NROW;                               // 8192 f32
    float* pos_acc = colacc + NROW;
    float* logsum = pos_acc + 1;
    unsigned* done_ct = (unsigned*)(logsum + 1);
    float* out = (float*)d_out;

    hipLaunchKernelGGL(k_normalize, dim3(NROW / 4), dim3(256), 0, stream,
                       xi, xj, z8, rowacc, colacc, pos_acc, logsum, done_ct);
    hipLaunchKernelGGL(k_gemm, dim3(512 + 64), dim3(512), 0, stream,
                       z8, rowacc, colacc, pos_acc);
    hipLaunchKernelGGL(k_logsum, dim3(NROW / 256), dim3(256), 0, stream,
                       rowacc, colacc, pos_acc, logsum, done_ct, out);
}